// Round 6
// baseline (14276.627 us; speedup 1.0000x reference)
//
#include <hip/hip_runtime.h>
#include <hip/hip_bf16.h>

#define SEQ   128
#define BATCH 64
#define EMB   128
#define CELL  128
#define VOCAB 10000
#define NPADV 10240          // vocab rows padded to /64
#define ROWS  8192           // SEQ*BATCH
#define GATES 512            // 4*CELL
#define INDIM 256            // EMB+CELL (gate weight row stride)

typedef short  short8 __attribute__((ext_vector_type(8)));
typedef float  f32x4  __attribute__((ext_vector_type(4)));
typedef unsigned short u16;

static __device__ __forceinline__ u16 f2bf(float f) {
  union { float f; unsigned int u; } v; v.f = f;
  unsigned int u = v.u;
  return (u16)((u + 0x7fffu + ((u >> 16) & 1u)) >> 16);   // RNE
}
static __device__ __forceinline__ float fexp(float x) {
  return __builtin_amdgcn_exp2f(x * 1.44269504088896340736f);
}
static __device__ __forceinline__ float fsig(float x) {
  return __builtin_amdgcn_rcpf(1.0f + fexp(-x));
}
static __device__ __forceinline__ float ftanh(float x) {
  float e = fexp(2.0f * x);                 // e^(2x); overflows to inf -> returns 1 (ok)
  return 1.0f - 2.0f * __builtin_amdgcn_rcpf(e + 1.0f);
}

// ---------- prep kernels ----------
__global__ void k_convert_W(const float* __restrict__ W, u16* __restrict__ Wbf) {
  int idx = blockIdx.x * blockDim.x + threadIdx.x;
  if (idx >= NPADV * EMB) return;
  int v = idx >> 7, k = idx & 127;
  float val = (v < VOCAB) ? W[(size_t)v * EMB + k] : 0.f;
  Wbf[idx] = f2bf(val);
}

__global__ void k_build_gates(const float* __restrict__ Wc, const float* __restrict__ Bc,
                              const float* __restrict__ Wf, const float* __restrict__ Bf,
                              const float* __restrict__ Wi, const float* __restrict__ Bi,
                              const float* __restrict__ Wo, const float* __restrict__ Bo,
                              u16* __restrict__ Wall, float* __restrict__ Ball) {
  int idx = blockIdx.x * blockDim.x + threadIdx.x;
  if (idx < GATES * EMB) {
    int r = idx >> 7, k = idx & 127;
    int g = r >> 7, j = r & 127;
    const float* Wg = (g == 0) ? Wc : (g == 1) ? Wf : (g == 2) ? Wi : Wo;
    Wall[idx] = f2bf(Wg[(size_t)j * INDIM + k]);          // embedding-part columns 0..127
  }
  if (idx < GATES) {
    int g = idx >> 7, j = idx & 127;
    const float* Bg = (g == 0) ? Bc : (g == 1) ? Bf : (g == 2) ? Bi : Bo;
    Ball[idx] = Bg[j];
  }
}

__global__ void k_gather_xe(const int* __restrict__ x, const float* __restrict__ emb,
                            u16* __restrict__ Xe) {
  int idx = blockIdx.x * blockDim.x + threadIdx.x;
  if (idx >= ROWS * EMB) return;
  int c = idx >> 7, e = idx & 127;
  int tok = x[c];                                         // x is [SEQ][BATCH], c = t*64+b
  Xe[idx] = f2bf(emb[(size_t)tok * EMB + e]);
}

// ---------- small bf16 MFMA GEMM (Zin): out[row][col] = A[row]·B[col] + bias[col] ----------
__launch_bounds__(256)
__global__ void k_gemm(const u16* __restrict__ A, const u16* __restrict__ B,
                       const float* __restrict__ bias, float* __restrict__ out,
                       int Nout) {
  __shared__ float tile[64][68];
  int lane = threadIdx.x & 63;
  int wave = threadIdx.x >> 6;
  int lr = lane & 15;
  int kh = lane >> 4;
  int rowbase = blockIdx.y * 64;
  int colblk  = blockIdx.x * 64;
  int colbase = colblk + wave * 16;

  const short8* A8 = (const short8*)A;
  const short8* B8 = (const short8*)B;

  f32x4 acc[4] = {};
#pragma unroll
  for (int ks = 0; ks < 4; ++ks) {
    short8 bfrag = B8[(size_t)(colbase + lr) * 16 + ks * 4 + kh];
#pragma unroll
    for (int m = 0; m < 4; ++m) {
      short8 afrag = A8[(size_t)(rowbase + m * 16 + lr) * 16 + ks * 4 + kh];
      acc[m] = __builtin_amdgcn_mfma_f32_16x16x32_bf16(afrag, bfrag, acc[m], 0, 0, 0);
    }
  }

#pragma unroll
  for (int m = 0; m < 4; ++m)
#pragma unroll
    for (int q = 0; q < 4; ++q)
      tile[m * 16 + kh * 4 + q][wave * 16 + lr] = acc[m][q];
  __syncthreads();

  int col4 = lane & 15;
  int c = colblk + col4 * 4;
  if (c < Nout) {
    f32x4 bv = {};
    if (bias) bv = *(const f32x4*)(bias + c);
#pragma unroll
    for (int i = 0; i < 4; ++i) {
      int r = wave * 16 + i * 4 + (lane >> 4);
      f32x4 v = *(const f32x4*)(&tile[r][col4 * 4]);
      v += bv;
      *(f32x4*)(out + (size_t)(rowbase + r) * Nout + c) = v;
    }
  }
}

// ---------- vocab projection v4: few DRAM row-streams + continuous stores ----------
// 128 blocks x 64-row bands. Within a block, all 8 waves work the SAME 16-row
// sub-band, interleaving 16-col groups (wave wv takes g % 8 == wv): only 16 output
// rows open per block (2048 device-wide vs 32768 in v3 -> DRAM row-buffer hits),
// and the 8 waves lay down adjacent 64B chunks ~= sequential runs per row.
// Register-direct f32x4 stores from acc, no LDS, no barriers (duty stays ~100%).
__launch_bounds__(512, 1)
__global__ void k_vocab4(const u16* __restrict__ A, const u16* __restrict__ B,
                         const float* __restrict__ bias, float* __restrict__ out) {
  int tid = threadIdx.x;
  int lane = tid & 63, wv = tid >> 6;       // 8 waves
  int lr = lane & 15, kh = lane >> 4;
  int rowblk = blockIdx.x * 64;

  const short8* A8 = (const short8*)A;
  const short8* B8 = (const short8*)B;

  for (int sb = 0; sb < 4; ++sb) {
    int rowbase = rowblk + sb * 16;
    short8 af[4];
#pragma unroll
    for (int ks = 0; ks < 4; ++ks)
      af[ks] = A8[(size_t)(rowbase + lr) * 16 + ks * 4 + kh];

    short8 vf[2][4];
    f32x4 bv[2];
    {
      int g0 = wv;                          // first group for this wave
#pragma unroll
      for (int ks = 0; ks < 4; ++ks)
        vf[0][ks] = B8[(size_t)(g0 * 16 + lr) * 16 + ks * 4 + kh];
      bv[0] = (g0 * 16 < VOCAB) ? *(const f32x4*)(bias + g0 * 16 + kh * 4) : f32x4{};
    }

    for (int gi = 0; gi < 80; ++gi) {       // 640 groups / 8 waves
      int cur = gi & 1, nxt = cur ^ 1;
      int g = gi * 8 + wv;
      if (gi + 1 < 80) {
        int gn = (gi + 1) * 8 + wv;
#pragma unroll
        for (int ks = 0; ks < 4; ++ks)
          vf[nxt][ks] = B8[(size_t)(gn * 16 + lr) * 16 + ks * 4 + kh];
        bv[nxt] = (gn * 16 < VOCAB) ? *(const f32x4*)(bias + gn * 16 + kh * 4) : f32x4{};
      }

      f32x4 acc = {};
#pragma unroll
      for (int ks = 0; ks < 4; ++ks)
        acc = __builtin_amdgcn_mfma_f32_16x16x32_bf16(vf[cur][ks], af[ks], acc, 0, 0, 0);

      int colg = g * 16;
      if (colg < VOCAB) {                   // VOCAB%16==0: group fully valid or not
        acc += bv[cur];
        *(f32x4*)(out + (size_t)(rowbase + lr) * VOCAB + colg + kh * 4) = acc;
      }
    }
  }
}

// ---------- sequential LSTM recurrence: one workgroup per batch column ----------
// 512 threads; thread r owns gate row r. Wh row (128 f32) in VGPRs; H broadcast via
// v_readlane. Zin prefetched 2 steps ahead (hides ~900cy HBM/L3 latency per step).
__launch_bounds__(512, 2)
__global__ void k_recur(const float* __restrict__ Wc, const float* __restrict__ Wf,
                        const float* __restrict__ Wi, const float* __restrict__ Wo,
                        const float* __restrict__ Zin, u16* __restrict__ Hbf,
                        float* __restrict__ outHC) {
  __shared__ float Hl[CELL];
  __shared__ float zl[GATES];
  int tid = threadIdx.x;
  int b = blockIdx.x;
  int lane = tid & 63;
  int g = tid >> 7, j = tid & 127;
  const float* Wg = (g == 0) ? Wc : (g == 1) ? Wf : (g == 2) ? Wi : Wo;
  const float* wp = Wg + (size_t)j * INDIM + EMB;

  float w[128];
#pragma unroll
  for (int k = 0; k < 128; ++k) w[k] = wp[k];

  if (tid < CELL) Hl[tid] = 0.f;
  float C = 0.f;

  // rolling depth-2 Zin prefetch
  float zcur = Zin[(size_t)(0 * BATCH + b) * GATES + tid];
  float znxt = Zin[(size_t)(1 * BATCH + b) * GATES + tid];
  __syncthreads();

  for (int t = 0; t < SEQ; ++t) {
    float zv = zcur;
    zcur = znxt;
    if (t + 2 < SEQ)
      znxt = Zin[(size_t)((t + 2) * BATCH + b) * GATES + tid];

    float h0 = Hl[lane];
    float h1 = Hl[lane + 64];
    float a0 = 0.f, a1 = 0.f, a2 = 0.f, a3 = 0.f;
#pragma unroll
    for (int k = 0; k < 32; ++k) {
      float p0 = __uint_as_float(__builtin_amdgcn_readlane(__float_as_uint(h0), k));
      a0 += w[k] * p0;
      float p1 = __uint_as_float(__builtin_amdgcn_readlane(__float_as_uint(h0), k + 32));
      a1 += w[k + 32] * p1;
      float p2 = __uint_as_float(__builtin_amdgcn_readlane(__float_as_uint(h1), k));
      a2 += w[k + 64] * p2;
      float p3 = __uint_as_float(__builtin_amdgcn_readlane(__float_as_uint(h1), k + 32));
      a3 += w[k + 96] * p3;
    }
    zl[tid] = zv + (a0 + a1) + (a2 + a3);
    __syncthreads();
    int c = t * BATCH + b;
    if (tid < CELL) {
      float cand = ftanh(zl[tid]);
      float F = fsig(zl[CELL + tid]);
      float I = fsig(zl[2 * CELL + tid]);
      float O = fsig(zl[3 * CELL + tid]);
      C = F * C + I * cand;
      float H = ftanh(C) * O;
      Hl[tid] = H;
      Hbf[(size_t)c * CELL + tid] = f2bf(H);
      if (t == SEQ - 1) {
        outHC[(size_t)tid * BATCH + b] = H;
        outHC[(size_t)CELL * BATCH + (size_t)tid * BATCH + b] = C;
      }
    }
    __syncthreads();
  }
}

extern "C" void kernel_launch(void* const* d_in, const int* in_sizes, int n_in,
                              void* d_out, int out_size, void* d_ws, size_t ws_size,
                              hipStream_t stream) {
  const int*   x   = (const int*)d_in[0];
  const float* emb = (const float*)d_in[1];
  const float* Wc  = (const float*)d_in[2];
  const float* Bc  = (const float*)d_in[3];
  const float* Wf  = (const float*)d_in[4];
  const float* Bf  = (const float*)d_in[5];
  const float* Wi  = (const float*)d_in[6];
  const float* Bi  = (const float*)d_in[7];
  const float* Wo  = (const float*)d_in[8];
  const float* Bo  = (const float*)d_in[9];
  const float* W   = (const float*)d_in[10];
  const float* b   = (const float*)d_in[11];
  float* out = (float*)d_out;

  char* ws = (char*)d_ws;
  size_t off = 0;
  auto alloc = [&](size_t bytes) -> void* {
    void* p = ws + off;
    off = (off + bytes + 255) & ~(size_t)255;
    return p;
  };
  u16*   Wbf  = (u16*)  alloc((size_t)NPADV * EMB * 2);   // 2.56 MB
  u16*   Wall = (u16*)  alloc((size_t)GATES * EMB * 2);   // 128 KB
  float* Ball = (float*)alloc((size_t)GATES * 4);         // 2 KB
  u16*   Xe   = (u16*)  alloc((size_t)ROWS * EMB * 2);    // 2 MB
  u16*   Hbf  = (u16*)  alloc((size_t)ROWS * CELL * 2);   // 2 MB
  float* Zin  = (float*)alloc((size_t)ROWS * GATES * 4);  // 16 MB

  hipLaunchKernelGGL(k_convert_W, dim3((NPADV * EMB + 255) / 256), dim3(256), 0, stream,
                     W, Wbf);
  hipLaunchKernelGGL(k_build_gates, dim3((GATES * EMB + 255) / 256), dim3(256), 0, stream,
                     Wc, Bc, Wf, Bf, Wi, Bi, Wo, Bo, Wall, Ball);
  hipLaunchKernelGGL(k_gather_xe, dim3((ROWS * EMB + 255) / 256), dim3(256), 0, stream,
                     x, emb, Xe);
  // Zin[c][r] = Xe[c]·Wall[r] + Ball[r]
  hipLaunchKernelGGL(k_gemm, dim3(GATES / 64, ROWS / 64), dim3(256), 0, stream,
                     Xe, Wall, Ball, Zin, GATES);
  // sequential recurrence, writes Hbf + final Ht/Ct
  hipLaunchKernelGGL(k_recur, dim3(BATCH), dim3(512), 0, stream,
                     Wc, Wf, Wi, Wo, Zin, Hbf, out + (size_t)ROWS * VOCAB);
  // out[c][v] = Hbf[c]·Wbf[v] + b[v]  (16-row sub-bands, 8 waves interleaved)
  hipLaunchKernelGGL(k_vocab4, dim3(ROWS / 64), dim3(512), 0, stream,
                     Hbf, Wbf, b, out);
}

// Round 7
// 268.603 us; speedup vs baseline: 53.1514x; 53.1514x over previous
//
#include <hip/hip_runtime.h>
#include <hip/hip_bf16.h>

#define SEQ   128
#define BATCH 64
#define EMB   128
#define CELL  128
#define VOCAB 10000
#define NPADV 10240          // vocab rows padded to /64
#define ROWS  8192           // SEQ*BATCH
#define GATES 512            // 4*CELL
#define INDIM 256            // EMB+CELL (gate weight row stride)

typedef short  short8 __attribute__((ext_vector_type(8)));
typedef float  f32x4  __attribute__((ext_vector_type(4)));
typedef unsigned short u16;

static __device__ __forceinline__ u16 f2bf(float f) {
  union { float f; unsigned int u; } v; v.f = f;
  unsigned int u = v.u;
  return (u16)((u + 0x7fffu + ((u >> 16) & 1u)) >> 16);   // RNE
}
static __device__ __forceinline__ float fexp(float x) {
  return __builtin_amdgcn_exp2f(x * 1.44269504088896340736f);
}
static __device__ __forceinline__ float fsig(float x) {
  return __builtin_amdgcn_rcpf(1.0f + fexp(-x));
}
static __device__ __forceinline__ float ftanh(float x) {
  float e = fexp(2.0f * x);                 // e^(2x); overflows to inf -> returns 1 (ok)
  return 1.0f - 2.0f * __builtin_amdgcn_rcpf(e + 1.0f);
}

// ---------- prep kernels ----------
__global__ void k_convert_W(const float* __restrict__ W, u16* __restrict__ Wbf) {
  int idx = blockIdx.x * blockDim.x + threadIdx.x;
  if (idx >= NPADV * EMB) return;
  int v = idx >> 7, k = idx & 127;
  float val = (v < VOCAB) ? W[(size_t)v * EMB + k] : 0.f;
  Wbf[idx] = f2bf(val);
}

__global__ void k_build_gates(const float* __restrict__ Wc, const float* __restrict__ Bc,
                              const float* __restrict__ Wf, const float* __restrict__ Bf,
                              const float* __restrict__ Wi, const float* __restrict__ Bi,
                              const float* __restrict__ Wo, const float* __restrict__ Bo,
                              u16* __restrict__ Wall, float* __restrict__ Ball) {
  int idx = blockIdx.x * blockDim.x + threadIdx.x;
  if (idx < GATES * EMB) {
    int r = idx >> 7, k = idx & 127;
    int g = r >> 7, j = r & 127;
    const float* Wg = (g == 0) ? Wc : (g == 1) ? Wf : (g == 2) ? Wi : Wo;
    Wall[idx] = f2bf(Wg[(size_t)j * INDIM + k]);          // embedding-part columns 0..127
  }
  if (idx < GATES) {
    int g = idx >> 7, j = idx & 127;
    const float* Bg = (g == 0) ? Bc : (g == 1) ? Bf : (g == 2) ? Bi : Bo;
    Ball[idx] = Bg[j];
  }
}

__global__ void k_gather_xe(const int* __restrict__ x, const float* __restrict__ emb,
                            u16* __restrict__ Xe) {
  int idx = blockIdx.x * blockDim.x + threadIdx.x;
  if (idx >= ROWS * EMB) return;
  int c = idx >> 7, e = idx & 127;
  int tok = x[c];                                         // x is [SEQ][BATCH], c = t*64+b
  Xe[idx] = f2bf(emb[(size_t)tok * EMB + e]);
}

// ---------- small bf16 MFMA GEMM (Zin): out[row][col] = A[row]·B[col] + bias[col] ----------
__launch_bounds__(256)
__global__ void k_gemm(const u16* __restrict__ A, const u16* __restrict__ B,
                       const float* __restrict__ bias, float* __restrict__ out,
                       int Nout) {
  __shared__ float tile[64][68];
  int lane = threadIdx.x & 63;
  int wave = threadIdx.x >> 6;
  int lr = lane & 15;
  int kh = lane >> 4;
  int rowbase = blockIdx.y * 64;
  int colblk  = blockIdx.x * 64;
  int colbase = colblk + wave * 16;

  const short8* A8 = (const short8*)A;
  const short8* B8 = (const short8*)B;

  f32x4 acc[4] = {};
#pragma unroll
  for (int ks = 0; ks < 4; ++ks) {
    short8 bfrag = B8[(size_t)(colbase + lr) * 16 + ks * 4 + kh];
#pragma unroll
    for (int m = 0; m < 4; ++m) {
      short8 afrag = A8[(size_t)(rowbase + m * 16 + lr) * 16 + ks * 4 + kh];
      acc[m] = __builtin_amdgcn_mfma_f32_16x16x32_bf16(afrag, bfrag, acc[m], 0, 0, 0);
    }
  }

#pragma unroll
  for (int m = 0; m < 4; ++m)
#pragma unroll
    for (int q = 0; q < 4; ++q)
      tile[m * 16 + kh * 4 + q][wave * 16 + lr] = acc[m][q];
  __syncthreads();

  int col4 = lane & 15;
  int c = colblk + col4 * 4;
  if (c < Nout) {
    f32x4 bv = {};
    if (bias) bv = *(const f32x4*)(bias + c);
#pragma unroll
    for (int i = 0; i < 4; ++i) {
      int r = wave * 16 + i * 4 + (lane >> 4);
      f32x4 v = *(const f32x4*)(&tile[r][col4 * 4]);
      v += bv;
      *(f32x4*)(out + (size_t)(rowbase + r) * Nout + c) = v;
    }
  }
}

// ---------- vocab projection v3nt: operand-swapped MFMA, register-direct NT stores ----------
// acc = mfma(vocab_frag, row_frag): lane holds 4 CONSECUTIVE vocab cols of ONE output
// row -> f32x4 store straight from acc. No LDS, no barriers. NEW vs round 5: stores
// are NONTEMPORAL so the 320MB output stream doesn't evict B (2.56MB) from L2 —
// round-4 profile showed FETCH_SIZE = 11.4GB (500x B's size) = write-induced thrash.
__launch_bounds__(256, 4)
__global__ void k_vocab3(const u16* __restrict__ A, const u16* __restrict__ B,
                         const float* __restrict__ bias, float* __restrict__ out) {
  int tid = threadIdx.x;
  int lane = tid & 63, wv = tid >> 6;
  int lr = lane & 15, kh = lane >> 4;
  int band  = blockIdx.x >> 2;            // 256 bands of 32 rows
  int slice = blockIdx.x & 3;             // 4 col-slices of 2560
  int rowbase = band * 32;
  int colbase = slice * 2560 + wv * 640;  // this wave: 40 groups of 16 cols

  const short8* A8 = (const short8*)A;
  const short8* B8 = (const short8*)B;

  short8 af0[4], af1[4];
#pragma unroll
  for (int ks = 0; ks < 4; ++ks) {
    af0[ks] = A8[(size_t)(rowbase + lr) * 16 + ks * 4 + kh];
    af1[ks] = A8[(size_t)(rowbase + 16 + lr) * 16 + ks * 4 + kh];
  }

  short8 vf[2][4];
  f32x4 bv[2];
#pragma unroll
  for (int ks = 0; ks < 4; ++ks)
    vf[0][ks] = B8[(size_t)(colbase + lr) * 16 + ks * 4 + kh];
  bv[0] = *(const f32x4*)(bias + colbase + kh * 4);

  for (int g = 0; g < 40; ++g) {
    int cur = g & 1, nxt = cur ^ 1;
    if (g + 1 < 40) {
      int cg = colbase + (g + 1) * 16;
#pragma unroll
      for (int ks = 0; ks < 4; ++ks)
        vf[nxt][ks] = B8[(size_t)(cg + lr) * 16 + ks * 4 + kh];
      bv[nxt] = *(const f32x4*)(bias + cg + kh * 4);
    }

    f32x4 a0 = {}, a1 = {};
#pragma unroll
    for (int ks = 0; ks < 4; ++ks) {
      a0 = __builtin_amdgcn_mfma_f32_16x16x32_bf16(vf[cur][ks], af0[ks], a0, 0, 0, 0);
      a1 = __builtin_amdgcn_mfma_f32_16x16x32_bf16(vf[cur][ks], af1[ks], a1, 0, 0, 0);
    }

    int colg = colbase + g * 16;
    if (colg < VOCAB) {                   // VOCAB%16==0: whole group valid or not
      int c = colg + kh * 4;
      a0 += bv[cur];
      a1 += bv[cur];
      __builtin_nontemporal_store(a0, (f32x4*)(out + (size_t)(rowbase + lr) * VOCAB + c));
      __builtin_nontemporal_store(a1, (f32x4*)(out + (size_t)(rowbase + 16 + lr) * VOCAB + c));
    }
  }
}

// ---------- sequential LSTM recurrence: one workgroup per batch column ----------
// 512 threads; thread r owns gate row r. Wh row (128 f32) in VGPRs; H broadcast via
// v_readlane. Zin prefetched 2 steps ahead (hides ~900cy HBM/L3 latency per step).
__launch_bounds__(512, 2)
__global__ void k_recur(const float* __restrict__ Wc, const float* __restrict__ Wf,
                        const float* __restrict__ Wi, const float* __restrict__ Wo,
                        const float* __restrict__ Zin, u16* __restrict__ Hbf,
                        float* __restrict__ outHC) {
  __shared__ float Hl[CELL];
  __shared__ float zl[GATES];
  int tid = threadIdx.x;
  int b = blockIdx.x;
  int lane = tid & 63;
  int g = tid >> 7, j = tid & 127;
  const float* Wg = (g == 0) ? Wc : (g == 1) ? Wf : (g == 2) ? Wi : Wo;
  const float* wp = Wg + (size_t)j * INDIM + EMB;

  float w[128];
#pragma unroll
  for (int k = 0; k < 128; ++k) w[k] = wp[k];

  if (tid < CELL) Hl[tid] = 0.f;
  float C = 0.f;

  // rolling depth-2 Zin prefetch
  float zcur = Zin[(size_t)(0 * BATCH + b) * GATES + tid];
  float znxt = Zin[(size_t)(1 * BATCH + b) * GATES + tid];
  __syncthreads();

  for (int t = 0; t < SEQ; ++t) {
    float zv = zcur;
    zcur = znxt;
    if (t + 2 < SEQ)
      znxt = Zin[(size_t)((t + 2) * BATCH + b) * GATES + tid];

    float h0 = Hl[lane];
    float h1 = Hl[lane + 64];
    float a0 = 0.f, a1 = 0.f, a2 = 0.f, a3 = 0.f;
#pragma unroll
    for (int k = 0; k < 32; ++k) {
      float p0 = __uint_as_float(__builtin_amdgcn_readlane(__float_as_uint(h0), k));
      a0 += w[k] * p0;
      float p1 = __uint_as_float(__builtin_amdgcn_readlane(__float_as_uint(h0), k + 32));
      a1 += w[k + 32] * p1;
      float p2 = __uint_as_float(__builtin_amdgcn_readlane(__float_as_uint(h1), k));
      a2 += w[k + 64] * p2;
      float p3 = __uint_as_float(__builtin_amdgcn_readlane(__float_as_uint(h1), k + 32));
      a3 += w[k + 96] * p3;
    }
    zl[tid] = zv + (a0 + a1) + (a2 + a3);
    __syncthreads();
    int c = t * BATCH + b;
    if (tid < CELL) {
      float cand = ftanh(zl[tid]);
      float F = fsig(zl[CELL + tid]);
      float I = fsig(zl[2 * CELL + tid]);
      float O = fsig(zl[3 * CELL + tid]);
      C = F * C + I * cand;
      float H = ftanh(C) * O;
      Hl[tid] = H;
      Hbf[(size_t)c * CELL + tid] = f2bf(H);
      if (t == SEQ - 1) {
        outHC[(size_t)tid * BATCH + b] = H;
        outHC[(size_t)CELL * BATCH + (size_t)tid * BATCH + b] = C;
      }
    }
    __syncthreads();
  }
}

extern "C" void kernel_launch(void* const* d_in, const int* in_sizes, int n_in,
                              void* d_out, int out_size, void* d_ws, size_t ws_size,
                              hipStream_t stream) {
  const int*   x   = (const int*)d_in[0];
  const float* emb = (const float*)d_in[1];
  const float* Wc  = (const float*)d_in[2];
  const float* Bc  = (const float*)d_in[3];
  const float* Wf  = (const float*)d_in[4];
  const float* Bf  = (const float*)d_in[5];
  const float* Wi  = (const float*)d_in[6];
  const float* Bi  = (const float*)d_in[7];
  const float* Wo  = (const float*)d_in[8];
  const float* Bo  = (const float*)d_in[9];
  const float* W   = (const float*)d_in[10];
  const float* b   = (const float*)d_in[11];
  float* out = (float*)d_out;

  char* ws = (char*)d_ws;
  size_t off = 0;
  auto alloc = [&](size_t bytes) -> void* {
    void* p = ws + off;
    off = (off + bytes + 255) & ~(size_t)255;
    return p;
  };
  u16*   Wbf  = (u16*)  alloc((size_t)NPADV * EMB * 2);   // 2.56 MB
  u16*   Wall = (u16*)  alloc((size_t)GATES * EMB * 2);   // 128 KB
  float* Ball = (float*)alloc((size_t)GATES * 4);         // 2 KB
  u16*   Xe   = (u16*)  alloc((size_t)ROWS * EMB * 2);    // 2 MB
  u16*   Hbf  = (u16*)  alloc((size_t)ROWS * CELL * 2);   // 2 MB
  float* Zin  = (float*)alloc((size_t)ROWS * GATES * 4);  // 16 MB

  hipLaunchKernelGGL(k_convert_W, dim3((NPADV * EMB + 255) / 256), dim3(256), 0, stream,
                     W, Wbf);
  hipLaunchKernelGGL(k_build_gates, dim3((GATES * EMB + 255) / 256), dim3(256), 0, stream,
                     Wc, Bc, Wf, Bf, Wi, Bi, Wo, Bo, Wall, Ball);
  hipLaunchKernelGGL(k_gather_xe, dim3((ROWS * EMB + 255) / 256), dim3(256), 0, stream,
                     x, emb, Xe);
  // Zin[c][r] = Xe[c]·Wall[r] + Ball[r]
  hipLaunchKernelGGL(k_gemm, dim3(GATES / 64, ROWS / 64), dim3(256), 0, stream,
                     Xe, Wall, Ball, Zin, GATES);
  // sequential recurrence, writes Hbf + final Ht/Ct
  hipLaunchKernelGGL(k_recur, dim3(BATCH), dim3(512), 0, stream,
                     Wc, Wf, Wi, Wo, Zin, Hbf, out + (size_t)ROWS * VOCAB);
  // out[c][v] = Hbf[c]·Wbf[v] + b[v]  (register-direct nontemporal streaming stores)
  hipLaunchKernelGGL(k_vocab3, dim3(1024), dim3(256), 0, stream,
                     Hbf, Wbf, b, out);
}